// Round 4
// baseline (25717.673 us; speedup 1.0000x reference)
//
#include <hip/hip_runtime.h>
#include <math.h>

#define TT 2048
#define BB 64
#define II 64
#define HH 512
#define OO 32
#define OCC 8
#define QK 128   // k/h slice per WG (4-way split)

// d_out layout: output [T,B,32] | output_ctx [T,B,8] | rate_all [T,B,512]
#define OUT1_OFF ((size_t)TT * BB * OO)
#define RATE_OFF (OUT1_OFF + (size_t)TT * BB * OCC)

// d_ws layout:
//   P[B][4][2][HH] floats @ 0            (1 MB, step-parity double buffer)
//   flags int[B*4*16]     @ byte 1<<20   (16 KB, one 64B line per flag)
#define P_FLOATS ((size_t)BB * 4 * 2 * HH)
#define FLAG_BYTE_OFF ((size_t)1 << 20)
#define FLAG_BYTES (BB * 4 * 16 * sizeof(int))

// ---------------------------------------------------------------------------
// Prefold: pre[t,b,h] = x[t,b,:] @ Wi[h,:] + bi[h] + bh[h] + NS*noise[t,b,h]
// written INTO the rate region of d_out (scan reads row then overwrites it).
// 8 rows per 512-thread WG; Wi row for h=tid held in 64 VGPRs.
// ---------------------------------------------------------------------------
__global__ __launch_bounds__(512) void prefold(
    const float* __restrict__ x, const float* __restrict__ noise,
    const float* __restrict__ Wi, const float* __restrict__ bi,
    const float* __restrict__ bh, float* __restrict__ pre)
{
    __shared__ float xs[8][II];
    const int tid = threadIdx.x;
    const size_t row0 = (size_t)blockIdx.x * 8;

    const double SIG = 1.5 / sqrt(512.0);
    const float  NS  = (float)sqrt(2.0 * SIG * SIG / 0.1);

    float wi[II];
    #pragma unroll
    for (int k4 = 0; k4 < II / 4; ++k4)
        *(float4*)&wi[4 * k4] = *(const float4*)&Wi[(size_t)tid * II + 4 * k4];
    const float bsum = bi[tid] + bh[tid];

    xs[tid >> 6][tid & 63] = x[(row0 + (tid >> 6)) * II + (tid & 63)];
    __syncthreads();

    #pragma unroll 2
    for (int r = 0; r < 8; ++r) {
        float acc = bsum + NS * noise[(row0 + r) * HH + tid];
        #pragma unroll
        for (int k4 = 0; k4 < II / 4; ++k4) {
            float4 xv = *(const float4*)&xs[r][4 * k4];
            acc += wi[4*k4] * xv.x + wi[4*k4+1] * xv.y
                 + wi[4*k4+2] * xv.z + wi[4*k4+3] * xv.w;
        }
        pre[(row0 + r) * HH + tid] = acc;
    }
}

// ---------------------------------------------------------------------------
// Recurrent scan, 4-way split: WG (q, b) at bid = q*64 + b  (bids of one batch
// are congruent mod 8 -> same XCD under round-robin placement; correctness
// does not depend on it: flags use agent-scope acquire/release).
// WG owns k-slice AND h-slice [128q, 128q+128). Weights in VGPRs (64/thread).
// Wave wv = (kg 0..7, hg 0..1): kg -> 16 k's, thread -> 4 h at hg*256+lane*4.
// Per step: dot -> LDS reduce -> publish 512-float partial (parity dbuf) ->
// release flag -> spin 3 peers -> read 3x128 remote partials -> tanh update.
// ---------------------------------------------------------------------------
__global__ __launch_bounds__(1024) void rnn_scan4(
    const float* __restrict__ rate0,   // [B,H]
    const float* __restrict__ Wh,      // [H,H] row-major
    float* __restrict__ pre_rate,      // [T,B,H]: in = pre, out = rate
    float* __restrict__ P,             // [B][4][2][HH]
    int* __restrict__ flags)           // [B*4*16]
{
    const int bid = blockIdx.x;
    const int q   = bid >> 6;          // quarter 0..3
    const int b   = bid & 63;          // batch
    const int tid = threadIdx.x;
    const int lane = tid & 63;
    const int wv  = tid >> 6;          // 0..15
    const int kg  = wv >> 1;           // 0..7 -> 16 k's each
    const int hg  = wv & 1;
    const int hbase = hg * 256 + lane * 4;
    const int k0 = q * QK + kg * 16;

    __shared__ float st[QK];           // own state slice
    __shared__ float parts[8 * HH];    // per-kg partials (16 KB)

    // wrow[j][k] = Wh[hbase+j][k0+k] : pre[h] = sum_k rate[k]*Wh[h][k]
    float wrow[4][16];
    #pragma unroll
    for (int j = 0; j < 4; ++j)
        #pragma unroll
        for (int k4 = 0; k4 < 4; ++k4)
            *(float4*)&wrow[j][4 * k4] =
                *(const float4*)&Wh[(size_t)(hbase + j) * HH + k0 + 4 * k4];

    const bool myh = (tid >= q * QK) && (tid < q * QK + QK);
    float rd = 0.f;
    if (myh) rd = rate0[b * HH + tid];
    if (tid < QK) st[tid] = rate0[b * HH + q * QK + tid];
    int* myflag = &flags[(b * 4 + q) * 16];
    __syncthreads();

    for (int t = 0; t < TT; ++t) {
        const int par = t & 1;
        const size_t row = ((size_t)t * BB + b) * HH;

        float pre_val = 0.f;
        if (myh) pre_val = pre_rate[row + tid];   // early; hides under dot

        // ---- dot: acc_j = sum over this wave's 16 k of wrow[j][k]*st[k]
        float a0 = 0.f, a1 = 0.f, a2 = 0.f, a3 = 0.f;
        #pragma unroll
        for (int kk = 0; kk < 16; kk += 4) {
            float4 s4 = *(const float4*)&st[kg * 16 + kk];
            a0 += wrow[0][kk]*s4.x + wrow[0][kk+1]*s4.y + wrow[0][kk+2]*s4.z + wrow[0][kk+3]*s4.w;
            a1 += wrow[1][kk]*s4.x + wrow[1][kk+1]*s4.y + wrow[1][kk+2]*s4.z + wrow[1][kk+3]*s4.w;
            a2 += wrow[2][kk]*s4.x + wrow[2][kk+1]*s4.y + wrow[2][kk+2]*s4.z + wrow[2][kk+3]*s4.w;
            a3 += wrow[3][kk]*s4.x + wrow[3][kk+1]*s4.y + wrow[3][kk+2]*s4.z + wrow[3][kk+3]*s4.w;
        }
        *(float4*)&parts[kg * HH + hbase] = make_float4(a0, a1, a2, a3);
        __syncthreads();                       // parts complete; st reads done

        // ---- reduce over kg and publish full 512-wide partial
        float sum = 0.f;
        if (tid < HH) {
            #pragma unroll
            for (int g = 0; g < 8; ++g) sum += parts[g * HH + tid];
            P[(((size_t)b * 4 + q) * 2 + par) * HH + tid] = sum;
        }
        __syncthreads();                       // drains all waves' stores

        if (tid == 0) {
            __hip_atomic_store(myflag, t + 1, __ATOMIC_RELEASE,
                               __HIP_MEMORY_SCOPE_AGENT);
            #pragma unroll
            for (int j = 1; j < 4; ++j) {
                int* f = &flags[(b * 4 + ((q + j) & 3)) * 16];
                while (__hip_atomic_load(f, __ATOMIC_ACQUIRE,
                                         __HIP_MEMORY_SCOPE_AGENT) < t + 1) {}
            }
        }
        __syncthreads();                       // peers' partials visible

        // ---- consume remote partials for own h-slice, update state
        if (myh) {
            float tot = sum + pre_val;
            #pragma unroll
            for (int j = 1; j < 4; ++j)
                tot += P[(((size_t)b * 4 + ((q + j) & 3)) * 2 + par) * HH + tid];
            rd = 0.9f * rd + 0.1f * tanhf(tot);
            pre_rate[row + tid] = rd;          // overwrite pre with rate
            st[tid - q * QK] = rd;
        }
        __syncthreads();                       // st ready for next dot
    }
}

// ---------------------------------------------------------------------------
// Readouts: 8 rows per 256-thread block, rows staged in LDS, float4 dots.
// ---------------------------------------------------------------------------
__global__ __launch_bounds__(256) void readout(
    const float* __restrict__ rate_all,
    const float* __restrict__ Wo,  const float* __restrict__ bo,
    const float* __restrict__ Woc, const float* __restrict__ boc,
    float* __restrict__ out, float* __restrict__ outc)
{
    __shared__ float rbuf[8][HH];
    const int tid  = threadIdx.x;
    const size_t row0 = (size_t)blockIdx.x * 8;

    for (int i = tid; i < 8 * (HH / 4); i += 256) {
        int r = i >> 7, c = (i & 127) * 4;
        *(float4*)&rbuf[r][c] = *(const float4*)&rate_all[(row0 + r) * HH + c];
    }
    __syncthreads();

    {
        int r = tid >> 5, o = tid & 31;
        const float* w = Wo + (size_t)o * HH;
        float acc = 0.f;
        #pragma unroll 4
        for (int h = 0; h < HH; h += 4) {
            float4 rv = *(const float4*)&rbuf[r][h];
            float4 wv = *(const float4*)&w[h];
            acc += rv.x * wv.x + rv.y * wv.y + rv.z * wv.z + rv.w * wv.w;
        }
        out[(row0 + r) * OO + o] = acc + bo[o];
    }
    if (tid < 64) {
        int r = tid >> 3, oc = tid & 7;
        const float* w = Woc + (size_t)oc * HH;
        float acc = 0.f;
        #pragma unroll 4
        for (int h = 0; h < HH; h += 4) {
            float4 rv = *(const float4*)&rbuf[r][h];
            float4 wv = *(const float4*)&w[h];
            acc += rv.x * wv.x + rv.y * wv.y + rv.z * wv.z + rv.w * wv.w;
        }
        outc[(row0 + r) * OCC + oc] = acc + boc[oc];
    }
}

// ---------------------------------------------------------------------------
extern "C" void kernel_launch(void* const* d_in, const int* in_sizes, int n_in,
                              void* d_out, int out_size, void* d_ws, size_t ws_size,
                              hipStream_t stream)
{
    const float* x     = (const float*)d_in[0];
    const float* rate0 = (const float*)d_in[1];
    const float* noise = (const float*)d_in[2];
    const float* Wi    = (const float*)d_in[3];
    const float* bi    = (const float*)d_in[4];
    const float* Wh    = (const float*)d_in[5];
    const float* bh    = (const float*)d_in[6];
    const float* Wo    = (const float*)d_in[7];
    const float* bo    = (const float*)d_in[8];
    const float* Woc   = (const float*)d_in[9];
    const float* boc   = (const float*)d_in[10];

    float* out   = (float*)d_out;
    float* rateb = out + RATE_OFF;            // pre, then rate
    float* P     = (float*)d_ws;
    int*   flags = (int*)((char*)d_ws + FLAG_BYTE_OFF);

    hipMemsetAsync(flags, 0, FLAG_BYTES, stream);   // ws is not re-poisoned
    prefold<<<TT * BB / 8, 512, 0, stream>>>(x, noise, Wi, bi, bh, rateb);
    rnn_scan4<<<4 * BB, 1024, 0, stream>>>(rate0, Wh, rateb, P, flags);
    readout<<<TT * BB / 8, 256, 0, stream>>>(rateb, Wo, bo, Woc, boc,
                                             out, out + OUT1_OFF);
}